// Round 2
// baseline (28146.490 us; speedup 1.0000x reference)
//
#include <hip/hip_runtime.h>
#include <hip/hip_cooperative_groups.h>

namespace cg = cooperative_groups;

#define HDIM 512
#define BATCH 32
#define SEQ 128
#define VOCAB 16384
#define NBLK 256      // cooperative grid blocks (1 per CU)
#define NGRU 128      // blocks participating in GRU phase (4 j's each)
#define NTHR 256

typedef unsigned long long u64;
typedef unsigned int u32;

static __device__ __forceinline__ float4 ld4(const float* p) {
    return *reinterpret_cast<const float4*>(p);
}
static __device__ __forceinline__ float dot4(float4 a, float4 b) {
    return a.x*b.x + a.y*b.y + a.z*b.z + a.w*b.w;
}
// monotone float->u32 map: a>b (floats, no NaN) <=> ford(a)>ford(b)
static __device__ __forceinline__ u32 ford(float f) {
    u32 b = __float_as_uint(f);
    return b ^ ((b >> 31) ? 0xFFFFFFFFu : 0x80000000u);
}
static __device__ __forceinline__ u64 shfl_xor_u64(u64 x, int m) {
    int lo = __shfl_xor((int)(u32)x, m);
    int hi = __shfl_xor((int)(u32)(x >> 32), m);
    return ((u64)(u32)hi << 32) | (u32)lo;
}

// GRU body — bit-identical arithmetic to the round-1 gru_step kernel.
// blk in [0,128): wave w owns j = blk*4+w; lane = kh*32 + b; 64x float4 over
// its 256-elem k-half; shfl_xor(32) combines halves.
static __device__ __forceinline__ void gru_body(
    int blk, int tid, const int* toks,
    const float* __restrict__ hin, float* __restrict__ hout,
    const float* __restrict__ Wih, const float* __restrict__ Whh,
    const float* __restrict__ bih, const float* __restrict__ bhh,
    const float* __restrict__ emb)
{
    const int wave = tid >> 6;
    const int lane = tid & 63;
    const int kh   = lane >> 5;
    const int b    = lane & 31;
    const int j    = blk * 4 + wave;

    const int tok = toks[b];
    const float* xrow = emb + (size_t)tok * HDIM + kh * 256;
    const float* hrow = hin + b * HDIM + kh * 256;
    const float* wir = Wih + (size_t)(0*HDIM + j) * HDIM + kh * 256;
    const float* wiz = Wih + (size_t)(1*HDIM + j) * HDIM + kh * 256;
    const float* win = Wih + (size_t)(2*HDIM + j) * HDIM + kh * 256;
    const float* whr = Whh + (size_t)(0*HDIM + j) * HDIM + kh * 256;
    const float* whz = Whh + (size_t)(1*HDIM + j) * HDIM + kh * 256;
    const float* whn = Whh + (size_t)(2*HDIM + j) * HDIM + kh * 256;

    float pr = 0.f, pz = 0.f, pxn = 0.f, phn = 0.f;
    #pragma unroll 4
    for (int k4 = 0; k4 < 64; ++k4) {
        float4 x4 = ld4(xrow + k4*4);
        float4 h4 = ld4(hrow + k4*4);
        pr  += dot4(x4, ld4(wir + k4*4)) + dot4(h4, ld4(whr + k4*4));
        pz  += dot4(x4, ld4(wiz + k4*4)) + dot4(h4, ld4(whz + k4*4));
        pxn += dot4(x4, ld4(win + k4*4));
        phn += dot4(h4, ld4(whn + k4*4));
    }
    pr  += __shfl_xor(pr, 32);
    pz  += __shfl_xor(pz, 32);
    pxn += __shfl_xor(pxn, 32);
    phn += __shfl_xor(phn, 32);

    if (kh == 0) {
        float r = 1.f / (1.f + expf(-(pr + bih[j]      + bhh[j])));
        float z = 1.f / (1.f + expf(-(pz + bih[HDIM+j] + bhh[HDIM+j])));
        float n = tanhf(pxn + bih[2*HDIM+j] + r * (phn + bhh[2*HDIM+j]));
        float hprev = hin[b * HDIM + j];
        hout[b * HDIM + j] = (1.f - z) * n + z * hprev;
    }
}

// ==================== persistent cooperative kernel ====================
__global__ __launch_bounds__(NTHR, 1) void seq2seq_main(
    const int* __restrict__ input,
    const float* __restrict__ enc_emb, const float* __restrict__ enc_Wih,
    const float* __restrict__ enc_Whh, const float* __restrict__ enc_bih,
    const float* __restrict__ enc_bhh,
    const float* __restrict__ dec_emb, const float* __restrict__ dec_Wih,
    const float* __restrict__ dec_Whh, const float* __restrict__ dec_bih,
    const float* __restrict__ dec_bhh,
    const float* __restrict__ out_W, const float* __restrict__ out_b,
    float* __restrict__ out, float* h0, float* h1, u64* pk)
{
    cg::grid_group grid = cg::this_grid();
    __shared__ int tok_s[BATCH];
    __shared__ u64 redk[BATCH][8];
    __shared__ float part[4][64][33];

    const int tid = threadIdx.x;
    const int blk = blockIdx.x;

    // ---- h0 = 0 ----
    if (blk < 16) {
        float4 z = {0.f, 0.f, 0.f, 0.f};
        *reinterpret_cast<float4*>(h0 + blk * 1024 + tid * 4) = z;
    }
    grid.sync();

    // ---- encoder: 128 steps ----
    for (int t = 0; t < SEQ; ++t) {
        float* hin  = (t & 1) ? h1 : h0;
        float* hout = (t & 1) ? h0 : h1;
        if (blk < NGRU) {
            if (tid < BATCH) tok_s[tid] = input[tid * SEQ + t];
            __syncthreads();
            gru_body(blk, tid, tok_s, hin, hout,
                     enc_Wih, enc_Whh, enc_bih, enc_bhh, enc_emb);
        }
        grid.sync();
    }

    // ---- decoder: 128 steps ----
    for (int t = 0; t < SEQ; ++t) {
        float* hin  = (t & 1) ? h1 : h0;
        float* hout = (t & 1) ? h0 : h1;

        if (blk < NGRU) {
            if (t == 0) {
                if (tid < BATCH) tok_s[tid] = 0;   // SOS
            } else {
                // finalize argmax over 256 packed partials per batch row
                const int b8 = tid >> 3, c8 = tid & 7;
                const u64* p = pk + b8 * NBLK + c8 * 32;
                u64 best = p[0];
                #pragma unroll 4
                for (int k = 1; k < 32; ++k) { u64 v = p[k]; if (v > best) best = v; }
                redk[b8][c8] = best;
                __syncthreads();
                if (tid < BATCH) {
                    u64 bb = redk[tid][0];
                    #pragma unroll
                    for (int c2 = 1; c2 < 8; ++c2) { u64 v = redk[tid][c2]; if (v > bb) bb = v; }
                    tok_s[tid] = (int)(~(u32)bb);
                }
            }
            __syncthreads();
            gru_body(blk, tid, tok_s, hin, hout,
                     dec_Wih, dec_Whh, dec_bih, dec_bhh, dec_emb);
        }
        grid.sync();

        // ---- logits + argmax partials (all 256 blocks, 64 vocab rows each) ----
        {
            const int vloc = tid & 63;
            const int ks   = __builtin_amdgcn_readfirstlane(tid >> 6);
            const int v    = blk * 64 + vloc;

            float acc[BATCH];
            #pragma unroll
            for (int b = 0; b < BATCH; ++b) acc[b] = 0.f;

            const float* wrow = out_W + (size_t)v * HDIM + ks * 128;
            const float* hq   = hout + ks * 128;

            for (int k4 = 0; k4 < 32; ++k4) {
                float4 w4 = ld4(wrow + k4*4);
                #pragma unroll
                for (int b = 0; b < BATCH; ++b) {
                    acc[b] += dot4(w4, ld4(hq + b * HDIM + k4*4));
                }
            }
            #pragma unroll
            for (int b = 0; b < BATCH; ++b) part[ks][vloc][b] = acc[b];
            __syncthreads();

            const int bg = tid >> 6;
            const float vbias = out_b[v];
            #pragma unroll
            for (int i = 0; i < 8; ++i) {
                const int b = bg * 8 + i;
                float s = part[0][vloc][b] + part[1][vloc][b]
                        + part[2][vloc][b] + part[3][vloc][b] + vbias;
                out[(size_t)b * (SEQ * VOCAB) + (size_t)t * VOCAB + v] = s;

                u64 key = ((u64)ford(s) << 32) | (u32)(~(u32)v);
                #pragma unroll
                for (int d = 1; d < 64; d <<= 1) {
                    u64 o = shfl_xor_u64(key, d);
                    if (o > key) key = o;
                }
                if (vloc == 0) pk[b * NBLK + blk] = key;
            }
            __syncthreads();   // part reused next step (also guarded by grid.sync)
        }
        grid.sync();
    }

    // ---- final decoder hidden -> out tail (h is in h0 after t=127) ----
    if (blk < 16) {
        *reinterpret_cast<float4*>(out + (size_t)BATCH * SEQ * VOCAB + blk * 1024 + tid * 4) =
            ld4(h0 + blk * 1024 + tid * 4);
    }
}

// ==================== fallback multi-kernel path (round-1) ====================
__global__ __launch_bounds__(256) void zero_kernel(float* __restrict__ p, int n) {
    int i = blockIdx.x * 256 + threadIdx.x;
    if (i < n) p[i] = 0.f;
}

__global__ __launch_bounds__(256) void gru_step(
    const float* __restrict__ h_in, float* __restrict__ h_out,
    const float* __restrict__ Wih, const float* __restrict__ Whh,
    const float* __restrict__ bih, const float* __restrict__ bhh,
    const float* __restrict__ emb,
    const int* __restrict__ enc_tokens, int t, const u64* __restrict__ pk)
{
    __shared__ int tok_s[BATCH];
    __shared__ u64 redk[BATCH][8];
    const int tid = threadIdx.x;

    if (enc_tokens != nullptr) {
        if (tid < BATCH) tok_s[tid] = enc_tokens[tid * SEQ + t];
    } else if (t == 0) {
        if (tid < BATCH) tok_s[tid] = 0;
    } else {
        const int b8 = tid >> 3, c8 = tid & 7;
        const u64* p = pk + b8 * NBLK + c8 * 32;
        u64 best = p[0];
        #pragma unroll 4
        for (int k = 1; k < 32; ++k) { u64 v = p[k]; if (v > best) best = v; }
        redk[b8][c8] = best;
        __syncthreads();
        if (tid < BATCH) {
            u64 bb = redk[tid][0];
            #pragma unroll
            for (int c2 = 1; c2 < 8; ++c2) { u64 v = redk[tid][c2]; if (v > bb) bb = v; }
            tok_s[tid] = (int)(~(u32)bb);
        }
    }
    __syncthreads();
    gru_body(blockIdx.x, tid, tok_s, h_in, h_out, Wih, Whh, bih, bhh, emb);
}

__global__ __launch_bounds__(256) void logits_kernel(
    const float* __restrict__ h, const float* __restrict__ outW,
    const float* __restrict__ outb, float* __restrict__ out,
    int t, u64* __restrict__ pk)
{
    __shared__ float part[4][64][33];
    const int tid  = threadIdx.x;
    const int vloc = tid & 63;
    const int ks   = __builtin_amdgcn_readfirstlane(tid >> 6);
    const int v    = blockIdx.x * 64 + vloc;

    float acc[BATCH];
    #pragma unroll
    for (int b = 0; b < BATCH; ++b) acc[b] = 0.f;

    const float* wrow = outW + (size_t)v * HDIM + ks * 128;
    const float* hq   = h + ks * 128;

    for (int k4 = 0; k4 < 32; ++k4) {
        float4 w4 = ld4(wrow + k4*4);
        #pragma unroll
        for (int b = 0; b < BATCH; ++b) acc[b] += dot4(w4, ld4(hq + b * HDIM + k4*4));
    }
    #pragma unroll
    for (int b = 0; b < BATCH; ++b) part[ks][vloc][b] = acc[b];
    __syncthreads();

    const int bg = tid >> 6;
    const float vbias = outb[v];
    #pragma unroll
    for (int i = 0; i < 8; ++i) {
        const int b = bg * 8 + i;
        float s = part[0][vloc][b] + part[1][vloc][b]
                + part[2][vloc][b] + part[3][vloc][b] + vbias;
        out[(size_t)b * (SEQ * VOCAB) + (size_t)t * VOCAB + v] = s;
        u64 key = ((u64)ford(s) << 32) | (u32)(~(u32)v);
        #pragma unroll
        for (int d = 1; d < 64; d <<= 1) {
            u64 o = shfl_xor_u64(key, d);
            if (o > key) key = o;
        }
        if (vloc == 0) pk[b * NBLK + blockIdx.x] = key;
    }
}

__global__ __launch_bounds__(256) void copy_kernel(const float* __restrict__ src,
                                                   float* __restrict__ dst, int n) {
    int i = blockIdx.x * 256 + threadIdx.x;
    if (i < n) dst[i] = src[i];
}

// ==================== deferred log_softmax ====================
__global__ __launch_bounds__(256) void softmax_kernel(float* __restrict__ out) {
    __shared__ float redm[4];
    __shared__ float reds[4];
    const int tid = threadIdx.x;
    float* p = out + (size_t)blockIdx.x * VOCAB;

    float4 vals[16];
    float m = -3.4e38f;
    #pragma unroll
    for (int i = 0; i < 16; ++i) {
        vals[i] = ld4(p + (i * 256 + tid) * 4);
        m = fmaxf(m, fmaxf(fmaxf(vals[i].x, vals[i].y), fmaxf(vals[i].z, vals[i].w)));
    }
    #pragma unroll
    for (int d = 1; d < 64; d <<= 1) m = fmaxf(m, __shfl_xor(m, d));
    if ((tid & 63) == 0) redm[tid >> 6] = m;
    __syncthreads();
    m = fmaxf(fmaxf(redm[0], redm[1]), fmaxf(redm[2], redm[3]));

    float s = 0.f;
    #pragma unroll
    for (int i = 0; i < 16; ++i) {
        s += expf(vals[i].x - m) + expf(vals[i].y - m)
           + expf(vals[i].z - m) + expf(vals[i].w - m);
    }
    #pragma unroll
    for (int d = 1; d < 64; d <<= 1) s += __shfl_xor(s, d);
    if ((tid & 63) == 0) reds[tid >> 6] = s;
    __syncthreads();
    s = reds[0] + reds[1] + reds[2] + reds[3];

    const float lg = m + logf(s);
    #pragma unroll
    for (int i = 0; i < 16; ++i) {
        float4 r;
        r.x = vals[i].x - lg; r.y = vals[i].y - lg;
        r.z = vals[i].z - lg; r.w = vals[i].w - lg;
        *reinterpret_cast<float4*>(p + (i * 256 + tid) * 4) = r;
    }
}

extern "C" void kernel_launch(void* const* d_in, const int* in_sizes, int n_in,
                              void* d_out, int out_size, void* d_ws, size_t ws_size,
                              hipStream_t stream) {
    const int*   input    = (const int*)  d_in[0];
    const float* enc_emb  = (const float*)d_in[1];
    const float* enc_Wih  = (const float*)d_in[2];
    const float* enc_Whh  = (const float*)d_in[3];
    const float* enc_bih  = (const float*)d_in[4];
    const float* enc_bhh  = (const float*)d_in[5];
    const float* dec_emb  = (const float*)d_in[6];
    const float* dec_Wih  = (const float*)d_in[7];
    const float* dec_Whh  = (const float*)d_in[8];
    const float* dec_bih  = (const float*)d_in[9];
    const float* dec_bhh  = (const float*)d_in[10];
    const float* out_W    = (const float*)d_in[11];
    const float* out_b    = (const float*)d_in[12];

    float* out = (float*)d_out;
    float* ws  = (float*)d_ws;

    float* h0 = ws;                       // 16384 floats
    float* h1 = ws + BATCH * HDIM;        // 16384 floats
    u64*   pk = (u64*)(ws + 2 * BATCH * HDIM);   // 32*256 u64 = 64KB

    void* args[] = {
        (void*)&input, (void*)&enc_emb, (void*)&enc_Wih, (void*)&enc_Whh,
        (void*)&enc_bih, (void*)&enc_bhh,
        (void*)&dec_emb, (void*)&dec_Wih, (void*)&dec_Whh, (void*)&dec_bih,
        (void*)&dec_bhh, (void*)&out_W, (void*)&out_b,
        (void*)&out, (void*)&h0, (void*)&h1, (void*)&pk
    };
    hipError_t rc = hipLaunchCooperativeKernel((void*)seq2seq_main,
                                               dim3(NBLK), dim3(NTHR),
                                               args, 0, stream);
    if (rc != hipSuccess) {
        // fallback: round-1 multi-kernel path
        zero_kernel<<<dim3((BATCH * HDIM + 255) / 256), dim3(256), 0, stream>>>(
            h0, BATCH * HDIM);
        float* hb[2] = { h0, h1 };
        for (int t = 0; t < SEQ; ++t) {
            gru_step<<<dim3(NGRU), dim3(256), 0, stream>>>(
                hb[t & 1], hb[(t + 1) & 1],
                enc_Wih, enc_Whh, enc_bih, enc_bhh, enc_emb, input, t, nullptr);
        }
        for (int t = 0; t < SEQ; ++t) {
            gru_step<<<dim3(NGRU), dim3(256), 0, stream>>>(
                hb[t & 1], hb[(t + 1) & 1],
                dec_Wih, dec_Whh, dec_bih, dec_bhh, dec_emb, nullptr, t, pk);
            logits_kernel<<<dim3(NBLK), dim3(256), 0, stream>>>(
                hb[(t + 1) & 1], out_W, out_b, out, t, pk);
        }
        copy_kernel<<<dim3((BATCH * HDIM + 255) / 256), dim3(256), 0, stream>>>(
            h0, out + (size_t)BATCH * SEQ * VOCAB, BATCH * HDIM);
    }

    softmax_kernel<<<dim3(BATCH * SEQ), dim3(256), 0, stream>>>(out);
}